// Round 17
// baseline (59.502 us; speedup 1.0000x reference)
//
#include <hip/hip_runtime.h>

#define B_ 4
#define C_ 256
#define H_ 64
#define W_ 64
#define HW_ 4096
#define K_ 7
#define P_ 3
#define KK_ 49
#define KKG_ 196
#define RED_ 32
#define NSTAT_ 16384.0f
#define BN_EPS_ 1e-5f
#define OCH_ 14              // span outputs per chunk (196 = 14*14)

// k_inv tile geometry
#define CPB_ 8               // channels per block
#define TH_ 16               // output rows per block
#define TRS_ 22              // TH_ + 6 halo rows
#define TRW_ 76              // 4 pad + 64 + 4 pad + 4 bank-skew

// ---------------- kernel 1: partial red = w_reduce @ x (R7/R12 proven) -------------
// grid (32, 4, 4); block 256. Thread = 2 consecutive pixels (float2).
__global__ __launch_bounds__(256) void k_reduce(const float* __restrict__ x,
                                               const float* __restrict__ wr,
                                               float4* __restrict__ part,
                                               float* __restrict__ gstats) {
    const int tid = threadIdx.x;
    const int og  = blockIdx.y;
    const int bz  = blockIdx.z;
    if (blockIdx.x == 0 && og == 0 && bz == 0 && tid < 64) gstats[tid] = 0.0f;

    const int p2 = blockIdx.x * 256 + tid;    // pixel-pair id, 0..8191
    const int b  = p2 >> 11;
    const int hw = (p2 & 2047) << 1;
    const float* xp = x + ((size_t)(b * C_ + bz * 64)) * HW_ + hw;
    const float* wp = wr + (og * 8) * C_ + bz * 64;

    float a[8][2];
#pragma unroll
    for (int oi = 0; oi < 8; ++oi) { a[oi][0] = 0.f; a[oi][1] = 0.f; }
#pragma unroll 8
    for (int cc = 0; cc < 64; ++cc) {
        const float2 v = *(const float2*)(xp + (size_t)cc * HW_);
#pragma unroll
        for (int oi = 0; oi < 8; ++oi) {
            const float wv = wp[oi * C_ + cc];        // wave-uniform -> s_load
            a[oi][0] = fmaf(wv, v.x, a[oi][0]);
            a[oi][1] = fmaf(wv, v.y, a[oi][1]);
        }
    }
    const int slot = bz * 4 + og;
    float4* pp0 = part + (((size_t)(slot * 2 + 0)) << 14) + (p2 << 1);
    float4* pp1 = part + (((size_t)(slot * 2 + 1)) << 14) + (p2 << 1);
    pp0[0] = make_float4(a[0][0], a[1][0], a[2][0], a[3][0]);
    pp0[1] = make_float4(a[0][1], a[1][1], a[2][1], a[3][1]);
    pp1[0] = make_float4(a[4][0], a[5][0], a[6][0], a[7][0]);
    pp1[1] = make_float4(a[4][1], a[5][1], a[6][1], a[7][1]);
}

// ---------------- kernel 1b: combine partials, write red, BN stats (R14 proven) ---
// grid (64, 8); block 256. XCD-swizzled so part reads are writer-local L2.
__global__ __launch_bounds__(256) void k_comb(const float4* __restrict__ part,
                                              float4* __restrict__ red,
                                              float* __restrict__ gsum,
                                              float* __restrict__ gsq) {
    __shared__ float lsum[4][8];
    const int tid  = threadIdx.x;
    const int lane = tid & 63;
    const int wv   = tid >> 6;
    const int oq   = blockIdx.y;        // 0..7
    const int bxp  = blockIdx.x;        // physical 0..63
    const int bxc  = ((bxp & 7) << 1) | ((bxp >> 3) & 1) | ((bxp >> 4) << 4);
    const int p    = bxc * 256 + tid;

    float4 s = make_float4(0.f, 0.f, 0.f, 0.f);
#pragma unroll
    for (int bz = 0; bz < 4; ++bz) {
        const float4 v = part[(((size_t)(bz * 8 + oq)) << 14) + p];
        s.x += v.x; s.y += v.y; s.z += v.z; s.w += v.w;
    }
    red[((size_t)oq << 14) + p] = s;

    float s0 = s.x, s1 = s.y, s2 = s.z, s3 = s.w;
    float q0 = s.x*s.x, q1 = s.y*s.y, q2 = s.z*s.z, q3 = s.w*s.w;
#pragma unroll
    for (int off = 32; off > 0; off >>= 1) {
        s0 += __shfl_down(s0, off);  q0 += __shfl_down(q0, off);
        s1 += __shfl_down(s1, off);  q1 += __shfl_down(q1, off);
        s2 += __shfl_down(s2, off);  q2 += __shfl_down(q2, off);
        s3 += __shfl_down(s3, off);  q3 += __shfl_down(q3, off);
    }
    if (lane == 0) {
        lsum[wv][0] = s0; lsum[wv][1] = s1; lsum[wv][2] = s2; lsum[wv][3] = s3;
        lsum[wv][4] = q0; lsum[wv][5] = q1; lsum[wv][6] = q2; lsum[wv][7] = q3;
    }
    __syncthreads();
    if (tid < 8) {
        const float v = lsum[0][tid] + lsum[1][tid] + lsum[2][tid] + lsum[3][tid];
        float* dst = (tid < 4) ? &gsum[oq * 4 + tid] : &gsq[oq * 4 + (tid - 4)];
        atomicAdd(dst, v);
    }
}

// ---------------- kernel 3: BN fold + act + ker = w_span @ act + b_span (R14) -----
// grid: (64, 14); block 256.
__global__ __launch_bounds__(256) void k_span(const float4* __restrict__ red,
                                              const float* __restrict__ wspan,
                                              const float* __restrict__ bspan,
                                              const float* __restrict__ gsum,
                                              const float* __restrict__ gsq,
                                              const float* __restrict__ gamma,
                                              const float* __restrict__ beta,
                                              float* __restrict__ ker) {
    __shared__ float sc_l[RED_], sh_l[RED_];
    const int tid   = threadIdx.x;
    const int chunk = blockIdx.y;
    const int obase = chunk * OCH_;
    if (tid < RED_) {
        const float m   = gsum[tid] * (1.0f / NSTAT_);
        const float var = gsq[tid] * (1.0f / NSTAT_) - m * m;
        const float inv = rsqrtf(var + BN_EPS_);
        const float sc  = gamma[tid] * inv;
        sc_l[tid] = sc;
        sh_l[tid] = beta[tid] - m * sc;
    }
    __syncthreads();

    const int p  = blockIdx.x * 256 + tid;
    const int b  = p >> 12;
    const int hw = p & 4095;

    float act[RED_];
#pragma unroll
    for (int og = 0; og < 8; ++og) {
        const float4 v = red[((size_t)og << 14) + p];
        act[4*og+0] = v.x; act[4*og+1] = v.y; act[4*og+2] = v.z; act[4*og+3] = v.w;
    }
#pragma unroll
    for (int o = 0; o < RED_; ++o)
        act[o] = fmaxf(fmaf(act[o], sc_l[o], sh_l[o]), 0.0f);

    float* kp = ker + ((size_t)b * KKG_ + obase) * HW_ + hw;
    const float* wp = wspan + (size_t)obase * RED_;
#pragma unroll 2
    for (int o = 0; o < OCH_; ++o) {
        float s = bspan[obase + o];
#pragma unroll
        for (int c = 0; c < RED_; ++c)
            s = fmaf(wp[o * RED_ + c], act[c], s);
        kp[(size_t)o * HW_] = s;
    }
}

// ---------------- kernel 4: involution, 8c x 16h x 64w, thread = 8c x 4w ----------
// grid 512, XCD-aware: bx = gid + 64*m. Per (i): all 7 kv taps loaded once into
// kv[7] and reused by 8 channels -> global kv loads 98 -> 49 per thread.
__global__ __launch_bounds__(256) void k_inv(const float* __restrict__ x,
                                             const float* __restrict__ ker,
                                             float* __restrict__ out) {
    __shared__ float tile[CPB_][TRS_][TRW_];   // 53504 B
    const int tid = threadIdx.x;
    const int wg  = tid & 15;           // 4-w group, w0 = wg*4
    const int hq  = tid >> 4;           // row in tile, 0..15
    const int bx  = blockIdx.x;
    const int gid = bx & 63;            // ker-tile group: (b,g,ht)
    const int m   = bx >> 6;            // member 0..7
    const int b   = gid >> 4;
    const int g   = (gid >> 2) & 3;
    const int ht  = gid & 3;
    const int cblk = (g << 3) + m;
    const int h0  = ht << 4;
    const int c0  = cblk << 3;
    const int w0  = wg << 2;
    const int h   = h0 + hq;

    const float4 fz = make_float4(0.f, 0.f, 0.f, 0.f);
#pragma unroll
    for (int it = 0; it < 11; ++it) {
        const int i   = it * 256 + tid;
        const int ci  = i / (TRS_ * 16);
        const int rem = i - ci * (TRS_ * 16);
        const int r   = rem >> 4;
        const int seg = rem & 15;
        const int hh  = h0 + r - P_;
        float4 v = fz;
        if (hh >= 0 && hh < H_)
            v = *(const float4*)(x + (((size_t)(b * C_ + c0 + ci)) << 12) + (hh << 6) + (seg << 2));
        *(float4*)&tile[ci][r][4 + (seg << 2)] = v;
    }
    for (int i = tid; i < CPB_ * TRS_ * 2; i += 256) {
        const int ci  = i / (TRS_ * 2);
        const int rem = i - ci * (TRS_ * 2);
        const int r   = rem >> 1;
        *(float4*)&tile[ci][r][(rem & 1) ? 68 : 0] = fz;
    }
    __syncthreads();

    const float* kp = ker + (((size_t)b * KKG_ + g * KK_) << 12) + (h << 6) + w0;

    float acc[8][4];
#pragma unroll
    for (int c = 0; c < 8; ++c)
#pragma unroll
        for (int dw = 0; dw < 4; ++dw) acc[c][dw] = 0.f;

#pragma unroll
    for (int i = 0; i < K_; ++i) {
        const int r = hq + i;
        float4 kv[7];
#pragma unroll
        for (int j = 0; j < K_; ++j)
            kv[j] = *(const float4*)(kp + ((size_t)(i * K_ + j) << 12));
#pragma unroll
        for (int c = 0; c < CPB_; ++c) {
            // tile cols w0..w0+11 = x cols (w0-4)..(w0+7); need (w0-3)..(w0+6)
            const float* t = &tile[c][r][w0];
            const float4 a0 = *(const float4*)(t);
            const float4 a1 = *(const float4*)(t + 4);
            const float4 a2 = *(const float4*)(t + 8);
            const float win[12] = {a0.x, a0.y, a0.z, a0.w,
                                   a1.x, a1.y, a1.z, a1.w,
                                   a2.x, a2.y, a2.z, a2.w};
#pragma unroll
            for (int j = 0; j < K_; ++j) {
                acc[c][0] = fmaf(kv[j].x, win[j + 1], acc[c][0]);
                acc[c][1] = fmaf(kv[j].y, win[j + 2], acc[c][1]);
                acc[c][2] = fmaf(kv[j].z, win[j + 3], acc[c][2]);
                acc[c][3] = fmaf(kv[j].w, win[j + 4], acc[c][3]);
            }
        }
    }

#pragma unroll
    for (int c = 0; c < CPB_; ++c)
        *(float4*)(out + (((size_t)(b * C_ + c0 + c)) << 12) + (h << 6) + w0) =
            make_float4(acc[c][0], acc[c][1], acc[c][2], acc[c][3]);
}

extern "C" void kernel_launch(void* const* d_in, const int* in_sizes, int n_in,
                              void* d_out, int out_size, void* d_ws, size_t ws_size,
                              hipStream_t stream) {
    const float* x     = (const float*)d_in[0];
    const float* wr    = (const float*)d_in[1];
    const float* gamma = (const float*)d_in[2];
    const float* beta  = (const float*)d_in[3];
    const float* wspan = (const float*)d_in[4];
    const float* bspan = (const float*)d_in[5];
    float* out = (float*)d_out;
    float* ws  = (float*)d_ws;

    // workspace layout (floats)
    float*  redf  = ws;                          // [8][16384] float4 = 524288 floats
    float*  gsum  = ws + 524288;                 // 32 (gsq contiguous after)
    float*  gsq   = gsum + 32;                   // 32
    float*  ker   = ws + 524416;                 // 4*196*4096 = 3211264 floats
    float*  partf = ws + 524416 + 3211264;       // [32][16384] float4 = 2097152 floats
    float4* red   = (float4*)redf;
    float4* part  = (float4*)partf;

    hipLaunchKernelGGL(k_reduce, dim3(32, 4, 4), dim3(256), 0, stream, x, wr, part, gsum);
    hipLaunchKernelGGL(k_comb,   dim3(64, 8),    dim3(256), 0, stream, part, red, gsum, gsq);
    hipLaunchKernelGGL(k_span,   dim3(64, 14),   dim3(256), 0, stream, red, wspan, bspan, gsum, gsq, gamma, beta, ker);
    hipLaunchKernelGGL(k_inv,    dim3(512),      dim3(256), 0, stream, x, ker, out);
}

// Round 18
// 58.564 us; speedup vs baseline: 1.0160x; 1.0160x over previous
//
#include <hip/hip_runtime.h>

#define B_ 4
#define C_ 256
#define H_ 64
#define W_ 64
#define HW_ 4096
#define K_ 7
#define P_ 3
#define KK_ 49
#define KKG_ 196
#define RED_ 32
#define NSTAT_ 16384.0f
#define BN_EPS_ 1e-5f
#define OCH_ 14              // span outputs per chunk (196 = 14*14)

// k_inv tile geometry (R10/R14 proven — LOCKED)
#define CPB_ 8               // channels per block
#define TH_ 16               // output rows per block
#define TRS_ 22              // TH_ + 6 halo rows
#define TRW_ 76              // 4 pad + 64 + 4 pad + 4 bank-skew

// ---------------- kernel 1: partial red = w_reduce @ x ----------------
// grid (32, 2, 8); block 256. Thread = 2 consecutive pixels (float2) x 16 o-ch.
// by = og (16 o-channels), bz = c-chunk (32 c). Weights via wave-uniform s_load.
// og=2/bz=8 minimizes x-redundancy + part traffic at fixed 512 blocks.
// part slot = bz*8 + og*4 + q  (== bz*8 + global o-quad) — matches k_comb.
__global__ __launch_bounds__(256) void k_reduce(const float* __restrict__ x,
                                               const float* __restrict__ wr,
                                               float4* __restrict__ part,
                                               float* __restrict__ gstats) {
    const int tid = threadIdx.x;
    const int og  = blockIdx.y;         // 0..1
    const int bz  = blockIdx.z;         // 0..7
    if (blockIdx.x == 0 && og == 0 && bz == 0 && tid < 64) gstats[tid] = 0.0f;

    const int p2 = blockIdx.x * 256 + tid;    // pixel-pair id, 0..8191
    const int b  = p2 >> 11;
    const int hw = (p2 & 2047) << 1;
    const float* xp = x + ((size_t)(b * C_ + bz * 32)) * HW_ + hw;
    const float* wp = wr + (og * 16) * C_ + bz * 32;

    float a[16][2];
#pragma unroll
    for (int oi = 0; oi < 16; ++oi) { a[oi][0] = 0.f; a[oi][1] = 0.f; }
#pragma unroll 8
    for (int cc = 0; cc < 32; ++cc) {
        const float2 v = *(const float2*)(xp + (size_t)cc * HW_);
#pragma unroll
        for (int oi = 0; oi < 16; ++oi) {
            const float wv = wp[oi * C_ + cc];        // wave-uniform -> s_load
            a[oi][0] = fmaf(wv, v.x, a[oi][0]);
            a[oi][1] = fmaf(wv, v.y, a[oi][1]);
        }
    }

#pragma unroll
    for (int q = 0; q < 4; ++q) {
        const int slot = bz * 8 + og * 4 + q;
        float4* pp = part + ((size_t)slot << 14) + (p2 << 1);
        pp[0] = make_float4(a[4*q+0][0], a[4*q+1][0], a[4*q+2][0], a[4*q+3][0]);
        pp[1] = make_float4(a[4*q+0][1], a[4*q+1][1], a[4*q+2][1], a[4*q+3][1]);
    }
}

// ---------------- kernel 1b: combine partials, write red, BN stats ----------------
// grid (64, 8); block 256. XCD-swizzled so part reads are writer-local L2.
// bz loop now 0..7 (8 partials).
__global__ __launch_bounds__(256) void k_comb(const float4* __restrict__ part,
                                              float4* __restrict__ red,
                                              float* __restrict__ gsum,
                                              float* __restrict__ gsq) {
    __shared__ float lsum[4][8];
    const int tid  = threadIdx.x;
    const int lane = tid & 63;
    const int wv   = tid >> 6;
    const int oq   = blockIdx.y;        // 0..7
    const int bxp  = blockIdx.x;        // physical 0..63
    const int bxc  = ((bxp & 7) << 1) | ((bxp >> 3) & 1) | ((bxp >> 4) << 4);
    const int p    = bxc * 256 + tid;

    float4 s = make_float4(0.f, 0.f, 0.f, 0.f);
#pragma unroll
    for (int bz = 0; bz < 8; ++bz) {
        const float4 v = part[(((size_t)(bz * 8 + oq)) << 14) + p];
        s.x += v.x; s.y += v.y; s.z += v.z; s.w += v.w;
    }
    red[((size_t)oq << 14) + p] = s;

    float s0 = s.x, s1 = s.y, s2 = s.z, s3 = s.w;
    float q0 = s.x*s.x, q1 = s.y*s.y, q2 = s.z*s.z, q3 = s.w*s.w;
#pragma unroll
    for (int off = 32; off > 0; off >>= 1) {
        s0 += __shfl_down(s0, off);  q0 += __shfl_down(q0, off);
        s1 += __shfl_down(s1, off);  q1 += __shfl_down(q1, off);
        s2 += __shfl_down(s2, off);  q2 += __shfl_down(q2, off);
        s3 += __shfl_down(s3, off);  q3 += __shfl_down(q3, off);
    }
    if (lane == 0) {
        lsum[wv][0] = s0; lsum[wv][1] = s1; lsum[wv][2] = s2; lsum[wv][3] = s3;
        lsum[wv][4] = q0; lsum[wv][5] = q1; lsum[wv][6] = q2; lsum[wv][7] = q3;
    }
    __syncthreads();
    if (tid < 8) {
        const float v = lsum[0][tid] + lsum[1][tid] + lsum[2][tid] + lsum[3][tid];
        float* dst = (tid < 4) ? &gsum[oq * 4 + tid] : &gsq[oq * 4 + (tid - 4)];
        atomicAdd(dst, v);
    }
}

// ---------------- kernel 3: BN fold + act + ker = w_span @ act + b_span (R14) -----
// grid: (64, 14); block 256.
__global__ __launch_bounds__(256) void k_span(const float4* __restrict__ red,
                                              const float* __restrict__ wspan,
                                              const float* __restrict__ bspan,
                                              const float* __restrict__ gsum,
                                              const float* __restrict__ gsq,
                                              const float* __restrict__ gamma,
                                              const float* __restrict__ beta,
                                              float* __restrict__ ker) {
    __shared__ float sc_l[RED_], sh_l[RED_];
    const int tid   = threadIdx.x;
    const int chunk = blockIdx.y;
    const int obase = chunk * OCH_;
    if (tid < RED_) {
        const float m   = gsum[tid] * (1.0f / NSTAT_);
        const float var = gsq[tid] * (1.0f / NSTAT_) - m * m;
        const float inv = rsqrtf(var + BN_EPS_);
        const float sc  = gamma[tid] * inv;
        sc_l[tid] = sc;
        sh_l[tid] = beta[tid] - m * sc;
    }
    __syncthreads();

    const int p  = blockIdx.x * 256 + tid;
    const int b  = p >> 12;
    const int hw = p & 4095;

    float act[RED_];
#pragma unroll
    for (int og = 0; og < 8; ++og) {
        const float4 v = red[((size_t)og << 14) + p];
        act[4*og+0] = v.x; act[4*og+1] = v.y; act[4*og+2] = v.z; act[4*og+3] = v.w;
    }
#pragma unroll
    for (int o = 0; o < RED_; ++o)
        act[o] = fmaxf(fmaf(act[o], sc_l[o], sh_l[o]), 0.0f);

    float* kp = ker + ((size_t)b * KKG_ + obase) * HW_ + hw;
    const float* wp = wspan + (size_t)obase * RED_;
#pragma unroll 2
    for (int o = 0; o < OCH_; ++o) {
        float s = bspan[obase + o];
#pragma unroll
        for (int c = 0; c < RED_; ++c)
            s = fmaf(wp[o * RED_ + c], act[c], s);
        kp[(size_t)o * HW_] = s;
    }
}

// ---------------- kernel 4: involution (R14 proven — LOCKED) ----------------
// 8c x 16h x 64w blocks, thread = 4c x 8w. grid 512, XCD-aware member mapping.
__global__ __launch_bounds__(256) void k_inv(const float* __restrict__ x,
                                             const float* __restrict__ ker,
                                             float* __restrict__ out) {
    __shared__ float tile[CPB_][TRS_][TRW_];   // 53504 B
    const int tid = threadIdx.x;
    const int wg  = tid & 7;            // 8-w group
    const int hq  = (tid >> 3) & 15;    // row in tile, 0..15
    const int cq  = tid >> 7;           // c-quad 0..1
    const int bx  = blockIdx.x;
    const int gid = bx & 63;            // ker-tile group: (b,g,ht)
    const int m   = bx >> 6;            // member 0..7
    const int b   = gid >> 4;
    const int g   = (gid >> 2) & 3;
    const int ht  = gid & 3;
    const int cblk = (g << 3) + m;
    const int h0  = ht << 4;
    const int c0  = cblk << 3;
    const int w0  = wg << 3;
    const int h   = h0 + hq;

    const float4 fz = make_float4(0.f, 0.f, 0.f, 0.f);
#pragma unroll
    for (int it = 0; it < 11; ++it) {
        const int i   = it * 256 + tid;
        const int ci  = i / (TRS_ * 16);
        const int rem = i - ci * (TRS_ * 16);
        const int r   = rem >> 4;
        const int seg = rem & 15;
        const int hh  = h0 + r - P_;
        float4 v = fz;
        if (hh >= 0 && hh < H_)
            v = *(const float4*)(x + (((size_t)(b * C_ + c0 + ci)) << 12) + (hh << 6) + (seg << 2));
        *(float4*)&tile[ci][r][4 + (seg << 2)] = v;
    }
    for (int i = tid; i < CPB_ * TRS_ * 2; i += 256) {
        const int ci  = i / (TRS_ * 2);
        const int rem = i - ci * (TRS_ * 2);
        const int r   = rem >> 1;
        *(float4*)&tile[ci][r][(rem & 1) ? 68 : 0] = fz;
    }
    __syncthreads();

    const int cA = cq << 2;
    const float* kp = ker + (((size_t)b * KKG_ + g * KK_) << 12) + (h << 6) + w0;

    float acc[4][8];
#pragma unroll
    for (int c = 0; c < 4; ++c)
#pragma unroll
        for (int dw = 0; dw < 8; ++dw) acc[c][dw] = 0.f;

#pragma unroll
    for (int i = 0; i < K_; ++i) {
        const int r = hq + i;
        float win[4][16];
#pragma unroll
        for (int c = 0; c < 4; ++c) {
            const float* t = &tile[cA + c][r][w0];
#pragma unroll
            for (int s = 0; s < 4; ++s) {
                const float4 v = *(const float4*)(t + (s << 2));
                win[c][4*s+0]=v.x; win[c][4*s+1]=v.y; win[c][4*s+2]=v.z; win[c][4*s+3]=v.w;
            }
        }
#pragma unroll
        for (int j = 0; j < K_; ++j) {
            const float* kpp = kp + ((size_t)(i * K_ + j) << 12);
            const float4 k0 = *(const float4*)kpp;
            const float4 k1 = *(const float4*)(kpp + 4);
            const float kv[8] = {k0.x, k0.y, k0.z, k0.w, k1.x, k1.y, k1.z, k1.w};
#pragma unroll
            for (int c = 0; c < 4; ++c)
#pragma unroll
                for (int dw = 0; dw < 8; ++dw)
                    acc[c][dw] = fmaf(kv[dw], win[c][dw + j + 1], acc[c][dw]);
        }
    }

#pragma unroll
    for (int c = 0; c < 4; ++c) {
        float* o = out + (((size_t)(b * C_ + c0 + cA + c)) << 12) + (h << 6) + w0;
        *(float4*)(o)     = make_float4(acc[c][0], acc[c][1], acc[c][2], acc[c][3]);
        *(float4*)(o + 4) = make_float4(acc[c][4], acc[c][5], acc[c][6], acc[c][7]);
    }
}

extern "C" void kernel_launch(void* const* d_in, const int* in_sizes, int n_in,
                              void* d_out, int out_size, void* d_ws, size_t ws_size,
                              hipStream_t stream) {
    const float* x     = (const float*)d_in[0];
    const float* wr    = (const float*)d_in[1];
    const float* gamma = (const float*)d_in[2];
    const float* beta  = (const float*)d_in[3];
    const float* wspan = (const float*)d_in[4];
    const float* bspan = (const float*)d_in[5];
    float* out = (float*)d_out;
    float* ws  = (float*)d_ws;

    // workspace layout (floats)
    float*  redf  = ws;                          // [8][16384] float4 = 524288 floats
    float*  gsum  = ws + 524288;                 // 32 (gsq contiguous after)
    float*  gsq   = gsum + 32;                   // 32
    float*  ker   = ws + 524416;                 // 4*196*4096 = 3211264 floats
    float*  partf = ws + 524416 + 3211264;       // [64][16384] float4 = 4194304 floats
    float4* red   = (float4*)redf;
    float4* part  = (float4*)partf;

    hipLaunchKernelGGL(k_reduce, dim3(32, 2, 8), dim3(256), 0, stream, x, wr, part, gsum);
    hipLaunchKernelGGL(k_comb,   dim3(64, 8),    dim3(256), 0, stream, part, red, gsum, gsq);
    hipLaunchKernelGGL(k_span,   dim3(64, 14),   dim3(256), 0, stream, red, wspan, bspan, gsum, gsq, gamma, beta, ker);
    hipLaunchKernelGGL(k_inv,    dim3(512),      dim3(256), 0, stream, x, ker, out);
}

// Round 19
// 54.358 us; speedup vs baseline: 1.0946x; 1.0774x over previous
//
#include <hip/hip_runtime.h>

#define B_ 4
#define C_ 256
#define H_ 64
#define W_ 64
#define HW_ 4096
#define K_ 7
#define P_ 3
#define KK_ 49
#define KKG_ 196
#define RED_ 32
#define NSTAT_ 16384.0f
#define BN_EPS_ 1e-5f
#define OCH_ 14              // span outputs per chunk (196 = 14*14)

// k_inv tile geometry (R10/R12/R14 proven — LOCKED)
#define CPB_ 8               // channels per block
#define TH_ 16               // output rows per block
#define TRS_ 22              // TH_ + 6 halo rows
#define TRW_ 76              // 4 pad + 64 + 4 pad + 4 bank-skew

// ---------------- kernel 1: partial red = w_reduce @ x (R7/R12 proven) -------------
// grid (32, 4, 4); block 256. Thread = 2 consecutive pixels (float2).
__global__ __launch_bounds__(256) void k_reduce(const float* __restrict__ x,
                                               const float* __restrict__ wr,
                                               float4* __restrict__ part,
                                               float* __restrict__ gstats) {
    const int tid = threadIdx.x;
    const int og  = blockIdx.y;
    const int bz  = blockIdx.z;
    if (blockIdx.x == 0 && og == 0 && bz == 0 && tid < 64) gstats[tid] = 0.0f;

    const int p2 = blockIdx.x * 256 + tid;    // pixel-pair id, 0..8191
    const int b  = p2 >> 11;
    const int hw = (p2 & 2047) << 1;
    const float* xp = x + ((size_t)(b * C_ + bz * 64)) * HW_ + hw;
    const float* wp = wr + (og * 8) * C_ + bz * 64;

    float a[8][2];
#pragma unroll
    for (int oi = 0; oi < 8; ++oi) { a[oi][0] = 0.f; a[oi][1] = 0.f; }
#pragma unroll 8
    for (int cc = 0; cc < 64; ++cc) {
        const float2 v = *(const float2*)(xp + (size_t)cc * HW_);
#pragma unroll
        for (int oi = 0; oi < 8; ++oi) {
            const float wv = wp[oi * C_ + cc];        // wave-uniform -> s_load
            a[oi][0] = fmaf(wv, v.x, a[oi][0]);
            a[oi][1] = fmaf(wv, v.y, a[oi][1]);
        }
    }
    const int slot = bz * 4 + og;
    float4* pp0 = part + (((size_t)(slot * 2 + 0)) << 14) + (p2 << 1);
    float4* pp1 = part + (((size_t)(slot * 2 + 1)) << 14) + (p2 << 1);
    pp0[0] = make_float4(a[0][0], a[1][0], a[2][0], a[3][0]);
    pp0[1] = make_float4(a[0][1], a[1][1], a[2][1], a[3][1]);
    pp1[0] = make_float4(a[4][0], a[5][0], a[6][0], a[7][0]);
    pp1[1] = make_float4(a[4][1], a[5][1], a[6][1], a[7][1]);
}

// ---------------- kernel 1b: combine partials, write red, BN stats (R14 proven) ---
// grid (64, 8); block 256. XCD-swizzled so part reads are writer-local L2.
__global__ __launch_bounds__(256) void k_comb(const float4* __restrict__ part,
                                              float4* __restrict__ red,
                                              float* __restrict__ gsum,
                                              float* __restrict__ gsq) {
    __shared__ float lsum[4][8];
    const int tid  = threadIdx.x;
    const int lane = tid & 63;
    const int wv   = tid >> 6;
    const int oq   = blockIdx.y;        // 0..7
    const int bxp  = blockIdx.x;        // physical 0..63
    const int bxc  = ((bxp & 7) << 1) | ((bxp >> 3) & 1) | ((bxp >> 4) << 4);
    const int p    = bxc * 256 + tid;

    float4 s = make_float4(0.f, 0.f, 0.f, 0.f);
#pragma unroll
    for (int bz = 0; bz < 4; ++bz) {
        const float4 v = part[(((size_t)(bz * 8 + oq)) << 14) + p];
        s.x += v.x; s.y += v.y; s.z += v.z; s.w += v.w;
    }
    red[((size_t)oq << 14) + p] = s;

    float s0 = s.x, s1 = s.y, s2 = s.z, s3 = s.w;
    float q0 = s.x*s.x, q1 = s.y*s.y, q2 = s.z*s.z, q3 = s.w*s.w;
#pragma unroll
    for (int off = 32; off > 0; off >>= 1) {
        s0 += __shfl_down(s0, off);  q0 += __shfl_down(q0, off);
        s1 += __shfl_down(s1, off);  q1 += __shfl_down(q1, off);
        s2 += __shfl_down(s2, off);  q2 += __shfl_down(q2, off);
        s3 += __shfl_down(s3, off);  q3 += __shfl_down(q3, off);
    }
    if (lane == 0) {
        lsum[wv][0] = s0; lsum[wv][1] = s1; lsum[wv][2] = s2; lsum[wv][3] = s3;
        lsum[wv][4] = q0; lsum[wv][5] = q1; lsum[wv][6] = q2; lsum[wv][7] = q3;
    }
    __syncthreads();
    if (tid < 8) {
        const float v = lsum[0][tid] + lsum[1][tid] + lsum[2][tid] + lsum[3][tid];
        float* dst = (tid < 4) ? &gsum[oq * 4 + tid] : &gsq[oq * 4 + (tid - 4)];
        atomicAdd(dst, v);
    }
}

// ---------------- kernel 3: BN fold + act + ker = w_span @ act + b_span (R14) -----
// grid: (64, 14); block 256.
__global__ __launch_bounds__(256) void k_span(const float4* __restrict__ red,
                                              const float* __restrict__ wspan,
                                              const float* __restrict__ bspan,
                                              const float* __restrict__ gsum,
                                              const float* __restrict__ gsq,
                                              const float* __restrict__ gamma,
                                              const float* __restrict__ beta,
                                              float* __restrict__ ker) {
    __shared__ float sc_l[RED_], sh_l[RED_];
    const int tid   = threadIdx.x;
    const int chunk = blockIdx.y;
    const int obase = chunk * OCH_;
    if (tid < RED_) {
        const float m   = gsum[tid] * (1.0f / NSTAT_);
        const float var = gsq[tid] * (1.0f / NSTAT_) - m * m;
        const float inv = rsqrtf(var + BN_EPS_);
        const float sc  = gamma[tid] * inv;
        sc_l[tid] = sc;
        sh_l[tid] = beta[tid] - m * sc;
    }
    __syncthreads();

    const int p  = blockIdx.x * 256 + tid;
    const int b  = p >> 12;
    const int hw = p & 4095;

    float act[RED_];
#pragma unroll
    for (int og = 0; og < 8; ++og) {
        const float4 v = red[((size_t)og << 14) + p];
        act[4*og+0] = v.x; act[4*og+1] = v.y; act[4*og+2] = v.z; act[4*og+3] = v.w;
    }
#pragma unroll
    for (int o = 0; o < RED_; ++o)
        act[o] = fmaxf(fmaf(act[o], sc_l[o], sh_l[o]), 0.0f);

    float* kp = ker + ((size_t)b * KKG_ + obase) * HW_ + hw;
    const float* wp = wspan + (size_t)obase * RED_;
#pragma unroll 2
    for (int o = 0; o < OCH_; ++o) {
        float s = bspan[obase + o];
#pragma unroll
        for (int c = 0; c < RED_; ++c)
            s = fmaf(wp[o * RED_ + c], act[c], s);
        kp[(size_t)o * HW_] = s;
    }
}

// ---------------- kernel 4: involution (R12/R14 proven — LOCKED) ----------------
// 8c x 16h x 64w blocks, thread = 4c x 8w. grid 512, XCD-aware member mapping.
__global__ __launch_bounds__(256) void k_inv(const float* __restrict__ x,
                                             const float* __restrict__ ker,
                                             float* __restrict__ out) {
    __shared__ float tile[CPB_][TRS_][TRW_];   // 53504 B
    const int tid = threadIdx.x;
    const int wg  = tid & 7;            // 8-w group
    const int hq  = (tid >> 3) & 15;    // row in tile, 0..15
    const int cq  = tid >> 7;           // c-quad 0..1
    const int bx  = blockIdx.x;
    const int gid = bx & 63;            // ker-tile group: (b,g,ht)
    const int m   = bx >> 6;            // member 0..7
    const int b   = gid >> 4;
    const int g   = (gid >> 2) & 3;
    const int ht  = gid & 3;
    const int cblk = (g << 3) + m;
    const int h0  = ht << 4;
    const int c0  = cblk << 3;
    const int w0  = wg << 3;
    const int h   = h0 + hq;

    const float4 fz = make_float4(0.f, 0.f, 0.f, 0.f);
#pragma unroll
    for (int it = 0; it < 11; ++it) {
        const int i   = it * 256 + tid;
        const int ci  = i / (TRS_ * 16);
        const int rem = i - ci * (TRS_ * 16);
        const int r   = rem >> 4;
        const int seg = rem & 15;
        const int hh  = h0 + r - P_;
        float4 v = fz;
        if (hh >= 0 && hh < H_)
            v = *(const float4*)(x + (((size_t)(b * C_ + c0 + ci)) << 12) + (hh << 6) + (seg << 2));
        *(float4*)&tile[ci][r][4 + (seg << 2)] = v;
    }
    for (int i = tid; i < CPB_ * TRS_ * 2; i += 256) {
        const int ci  = i / (TRS_ * 2);
        const int rem = i - ci * (TRS_ * 2);
        const int r   = rem >> 1;
        *(float4*)&tile[ci][r][(rem & 1) ? 68 : 0] = fz;
    }
    __syncthreads();

    const int cA = cq << 2;
    const float* kp = ker + (((size_t)b * KKG_ + g * KK_) << 12) + (h << 6) + w0;

    float acc[4][8];
#pragma unroll
    for (int c = 0; c < 4; ++c)
#pragma unroll
        for (int dw = 0; dw < 8; ++dw) acc[c][dw] = 0.f;

#pragma unroll
    for (int i = 0; i < K_; ++i) {
        const int r = hq + i;
        float win[4][16];
#pragma unroll
        for (int c = 0; c < 4; ++c) {
            const float* t = &tile[cA + c][r][w0];
#pragma unroll
            for (int s = 0; s < 4; ++s) {
                const float4 v = *(const float4*)(t + (s << 2));
                win[c][4*s+0]=v.x; win[c][4*s+1]=v.y; win[c][4*s+2]=v.z; win[c][4*s+3]=v.w;
            }
        }
#pragma unroll
        for (int j = 0; j < K_; ++j) {
            const float* kpp = kp + ((size_t)(i * K_ + j) << 12);
            const float4 k0 = *(const float4*)kpp;
            const float4 k1 = *(const float4*)(kpp + 4);
            const float kv[8] = {k0.x, k0.y, k0.z, k0.w, k1.x, k1.y, k1.z, k1.w};
#pragma unroll
            for (int c = 0; c < 4; ++c)
#pragma unroll
                for (int dw = 0; dw < 8; ++dw)
                    acc[c][dw] = fmaf(kv[dw], win[c][dw + j + 1], acc[c][dw]);
        }
    }

#pragma unroll
    for (int c = 0; c < 4; ++c) {
        float* o = out + (((size_t)(b * C_ + c0 + cA + c)) << 12) + (h << 6) + w0;
        *(float4*)(o)     = make_float4(acc[c][0], acc[c][1], acc[c][2], acc[c][3]);
        *(float4*)(o + 4) = make_float4(acc[c][4], acc[c][5], acc[c][6], acc[c][7]);
    }
}

extern "C" void kernel_launch(void* const* d_in, const int* in_sizes, int n_in,
                              void* d_out, int out_size, void* d_ws, size_t ws_size,
                              hipStream_t stream) {
    const float* x     = (const float*)d_in[0];
    const float* wr    = (const float*)d_in[1];
    const float* gamma = (const float*)d_in[2];
    const float* beta  = (const float*)d_in[3];
    const float* wspan = (const float*)d_in[4];
    const float* bspan = (const float*)d_in[5];
    float* out = (float*)d_out;
    float* ws  = (float*)d_ws;

    // workspace layout (floats)
    float*  redf  = ws;                          // [8][16384] float4 = 524288 floats
    float*  gsum  = ws + 524288;                 // 32 (gsq contiguous after)
    float*  gsq   = gsum + 32;                   // 32
    float*  ker   = ws + 524416;                 // 4*196*4096 = 3211264 floats
    float*  partf = ws + 524416 + 3211264;       // [32][16384] float4 = 2097152 floats
    float4* red   = (float4*)redf;
    float4* part  = (float4*)partf;

    hipLaunchKernelGGL(k_reduce, dim3(32, 4, 4), dim3(256), 0, stream, x, wr, part, gsum);
    hipLaunchKernelGGL(k_comb,   dim3(64, 8),    dim3(256), 0, stream, part, red, gsum, gsq);
    hipLaunchKernelGGL(k_span,   dim3(64, 14),   dim3(256), 0, stream, red, wspan, bspan, gsum, gsq, gamma, beta, ker);
    hipLaunchKernelGGL(k_inv,    dim3(512),      dim3(256), 0, stream, x, ker, out);
}